// Round 10
// baseline (203.569 us; speedup 1.0000x reference)
//
#include <hip/hip_runtime.h>
#include <hip/hip_bf16.h>

// B=2, M=2048, HID=1024, NH=16, D=64.  No softmax in the reference, so
//   out = ((h Wq^T)(h Wk^T)^T (h Wv^T)) Wo^T
// reassociates twice:  S_{b,h} = K_h^T V_h  (64x64), and
//   out_b = Q_b @ T_b   with  T_b[h*64+d, n] = sum_j S_{b,h}[d,j] Wo[n, h*64+j]
//
// Dtypes: inputs fp32, d_out fp32; internal bf16 with fp32 accumulate.
//
// Round-21: r20 (2-tiles/phase) tied r15/r16/r17 -- five structural GEMM
// variants within +-3us => the GEMMs are at this structure's plateau and
// per-kernel tuning stopped paying.  Accounting: all our dispatches are
// <41us (fills own top-5); sum of kernel times (~60us) + fills leaves tens
// of us of per-LAUNCH fixed cost as the largest untouched item.  r21 cuts
// kernel count: reduce_s is folded into s_kernel via a last-block pattern:
//   each chunk-block writes its partial, __threadfence() (release:
//   wbl2), atomicAdd(&cnt[bh],1); the block seeing old==15 does an
//   acquire __threadfence() (inv) and folds the 16 partials -> S.
// One atomic per BLOCK (not r6's per-element atomics) and ONE folder per
// bh reading 256KB (not r10's 8x redundant 64MB).  cnt[] is re-zeroed by
// prep each iteration (stream-ordered before s_kernel) => poison-safe.
// Fold order = reduce_s order => bit-identical S.  t_kernel unchanged.
// Lessons kept: no dense-reduction atomics (r6->r7); never trade
// high-occupancy FLOPs for low-occupancy FLOPs (r8); price redundant
// re-reads by XCD locality (r10); vmcnt waits are per-wave -- wait must
// precede a barrier (r12); count LDS bytes per phase (r13); grid must
// cover all 256 CUs (r14); don't serialize LDS and MFMA with explicit
// drains (r15); size the per-XCD L2 working set (r16); in-block schedule
// tweaks can't fix lockstep stalls (r17); when variants tie, cut work not
// tune (r18); FLOP cuts don't pay in the wait-bound regime (r19); when
// per-kernel tuning plateaus, cut LAUNCHES (r20).
//
// Pipeline (5 kernels):
//   0. prep: h->hb (bf16), Wq|Wk|Wv->wcat (bf16), zero cnt[32]
//   1. QKVb = hb @ wcat^T        (4096x3072 bf16)            [gemmP<384>]
//   2. Spart partials + last-block fold -> S                 [VALU+flag]
//   3. Tt[b][n,k] = (S_h Wo_h^T)^T  (2 x 1024x1024 bf16)     [VALU]
//   4. out = Q @ Tt_b^T          (4096x1024 fp32 -> d_out)   [gemmP<128>]

typedef unsigned short u16;
typedef unsigned int u32;
typedef __attribute__((ext_vector_type(8))) short bf16x8;
typedef __attribute__((ext_vector_type(4))) float f32x4;

__device__ __forceinline__ void async_copy16(void* lds, const void* g) {
  __builtin_amdgcn_global_load_lds((const __attribute__((address_space(1))) void*)g,
                                   (__attribute__((address_space(3))) void*)lds,
                                   16, 0, 0);
}

__device__ __forceinline__ u16 f2bf(float f) {
  union { __hip_bfloat16 h; u16 u; } c;
  c.h = __float2bfloat16(f);
  return c.u;
}
__device__ __forceinline__ float bflo(u32 w) {
  union { u32 u; float f; } c; c.u = w << 16; return c.f;
}
__device__ __forceinline__ float bfhi(u32 w) {
  union { u32 u; float f; } c; c.u = w & 0xFFFF0000u; return c.f;
}
__device__ __forceinline__ ushort4 cvt4(float4 v) {
  ushort4 o; o.x = f2bf(v.x); o.y = f2bf(v.y); o.z = f2bf(v.z); o.w = f2bf(v.w);
  return o;
}

template <int N> __device__ __forceinline__ void vw() {
  if constexpr (N == 4)      asm volatile("s_waitcnt vmcnt(4)" ::: "memory");
  else if constexpr (N == 2) asm volatile("s_waitcnt vmcnt(2)" ::: "memory");
  else if constexpr (N == 0) asm volatile("s_waitcnt vmcnt(0)" ::: "memory");
}

// ---------------------------------------------------------------- prep ------
__global__ __launch_bounds__(256) void prep(const float4* __restrict__ h,
                                            const float4* __restrict__ wq,
                                            const float4* __restrict__ wk,
                                            const float4* __restrict__ wv,
                                            ushort4* __restrict__ hb,
                                            ushort4* __restrict__ wcat,
                                            int* __restrict__ cnt) {
  if (blockIdx.x == 0 && threadIdx.x < 32) cnt[threadIdx.x] = 0;
  int i = blockIdx.x * 256 + threadIdx.x;  // float4 units
  if (i < 1048576) { hb[i] = cvt4(h[i]); return; }          // h: 4096x1024
  i -= 1048576;
  if (i < 262144) { wcat[i] = cvt4(wq[i]); return; }
  i -= 262144;
  if (i < 262144) { wcat[262144 + i] = cvt4(wk[i]); return; }
  i -= 262144;
  wcat[524288 + i] = cvt4(wv[i]);
}

// -------------------- BK=32, 2-tiles/phase, 5-buffer NT GEMM ----------------
// C[m,n] = sum_k A[m*lda+k] * B[n*1024+k], M=4096, K=1024, BM=128.
// grid 256 = 32 m x 8 n (r15 mapping), 512 thr = 8 waves (2x4).
// Phase p: {reads tile 2p | stage 2p+3 | MFMA | reads 2p+1 | stage 2p+4 |
// MFMA | lgkmcnt(0) | vw<V> | s_barrier | sched_barrier}.  16 phases.
// Safety: read bufs 2p%5,(2p+1)%5 vs write bufs (2p+3)%5,(2p+4)%5 all
// distinct mod 5; per-wave lgkmcnt(0) precedes the phase barrier (WAR);
// tiles 2p+2,2p+3 gated by all waves' vw<V>+barrier at end of phase p.

#define NOPW ((void)0)

#define TILE1(KT, DO_STAGE)                                                  \
  do {                                                                       \
    const u16* Ab = &Als[(KT) % 5][wm * 32 + aoff];                          \
    const u16* Bb = &Bls[(KT) % 5][wn * 32 + aoff];                          \
    bf16x8 af[MI], bv[NI];                                                   \
    _Pragma("unroll") for (int i = 0; i < MI; ++i)                           \
        af[i] = *(const bf16x8*)(Ab + i * 512);                              \
    _Pragma("unroll") for (int j = 0; j < NI; ++j)                           \
        bv[j] = *(const bf16x8*)(Bb + j * 512);                              \
    DO_STAGE;                                                                \
    __builtin_amdgcn_s_setprio(1);                                           \
    _Pragma("unroll") for (int i = 0; i < MI; ++i)                           \
        _Pragma("unroll") for (int j = 0; j < NI; ++j)                       \
            acc[i][j] = __builtin_amdgcn_mfma_f32_16x16x32_bf16(             \
                af[i], bv[j], acc[i][j], 0, 0, 0);                           \
    __builtin_amdgcn_s_setprio(0);                                           \
  } while (0)

#define PHASE2(KT, ST1, ST2, VWAIT)                                          \
  do {                                                                       \
    TILE1(KT, ST1);                                                          \
    TILE1((KT) + 1, ST2);                                                    \
    asm volatile("s_waitcnt lgkmcnt(0)" ::: "memory");                       \
    VWAIT;                                                                   \
    __builtin_amdgcn_s_barrier();                                            \
    __builtin_amdgcn_sched_barrier(0);                                       \
  } while (0)

template <bool BF16_OUT, int BN, int W>
__global__ __launch_bounds__(512, W) void gemmP(const u16* __restrict__ A,
                                                int lda,
                                                const u16* __restrict__ B0,
                                                const u16* __restrict__ B1,
                                                void* __restrict__ Cv,
                                                int N) {
  constexpr int SA = 1;              // A staging insts/thread (BM=128)
  constexpr int SB = BN / 128;       // B staging insts/thread
  constexpr int V  = SA + SB;        // insts/thread per K-tile
  constexpr int MI = 4;              // 64-row wave half
  constexpr int NI = BN / 4 / 16;

  __shared__ u16 Als[5][128 * 32];
  __shared__ u16 Bls[5][BN * 32];
  const int t = threadIdx.x;
  const int lane = t & 63;
  const int wave = t >> 6;                 // 0..7
  const int wm = (wave >> 2) * 64;         // 0 / 64
  const int wn = (wave & 3) * (BN / 4);
  const int lrow = lane & 15;
  const int quad = lane >> 4;

  // r15 mapping: XCD x -> m-tiles {4x..4x+3} x all 8 n-panels.
  const int bid = blockIdx.x;
  const int xcd = bid & 7;
  const int c = bid >> 3;                  // 0..31
  const int m0 = (xcd * 4 + (c >> 3)) * 128;
  const int n0 = (c & 7) * BN;
  const u16* B = (B1 != nullptr && m0 >= 2048) ? B1 : B0;

  // staging: one inst = 16 rows x 32 k = 1 KB; lane l -> row +(l>>2),
  // LDS slot l&3 holds global k-granule (l&3)^((l>>3)&3)  (linear dest).
  const int srow = lane >> 2;
  const int sgk  = (lane & 3) ^ ((lane >> 3) & 3);
  const u16* Ag = A + (size_t)(m0 + wave * (SA * 16) + srow) * lda + sgk * 8;
  const u16* Bg = B + (size_t)(n0 + wave * (SB * 16) + srow) * 1024 + sgk * 8;

  // read swizzle: slot of granule `quad` at row r is quad^((r>>1)&3);
  // row bases are multiples of 16 -> (r>>1)&3 == (lrow>>1)&3.
  const int swz = (lrow >> 1) & 3;
  const int aoff = lrow * 32 + ((quad ^ swz) << 3);

  f32x4 acc[MI][NI];
#pragma unroll
  for (int i = 0; i < MI; ++i)
#pragma unroll
    for (int j = 0; j < NI; ++j) acc[i][j] = {0.f, 0.f, 0.f, 0.f};

  auto stage = [&](int kt) {
    const int buf = kt % 5;
#pragma unroll
    for (int j = 0; j < SA; ++j) {
      const int ch = wave * SA + j;
      async_copy16(&Als[buf][ch * 512 + lane * 8],
                   Ag + (size_t)(j * 16) * lda + kt * 32);
    }
#pragma unroll
    for (int j = 0; j < SB; ++j) {
      const int ch = wave * SB + j;
      async_copy16(&Bls[buf][ch * 512 + lane * 8],
                   Bg + (size_t)(j * 16) * 1024 + kt * 32);
    }
  };

  // prologue: stage tiles 0,1,2 (3V insts); vw<V> -> tiles 0,1 resident,
  // tile 2 still in flight; barrier.
  stage(0); stage(1); stage(2);
  vw<V>();
  __builtin_amdgcn_s_barrier();
  __builtin_amdgcn_sched_barrier(0);

  // steady: 14 phases; phase p reads 2p,2p+1, stages 2p+3,2p+4;
  // vw<V> drains tiles 2p+2,2p+3, leaves 2p+4 in flight.
#pragma unroll 1
  for (int p = 0; p < 14; ++p) {
    PHASE2(2 * p, stage(2 * p + 3), stage(2 * p + 4), vw<V>());
  }
  // p=14: reads 28,29; stage 31 only; drain everything (tiles 30,31).
  PHASE2(28, stage(31), NOPW, vw<0>());
  // p=15: reads 30,31.
  PHASE2(30, NOPW, NOPW, NOPW);

  // C/D layout (verified m89/m91): col = lane&15, row = (lane>>4)*4 + r
  const int crow0 = m0 + wm + quad * 4;
  const int ccol0 = n0 + wn + lrow;
#pragma unroll
  for (int mf = 0; mf < MI; ++mf)
#pragma unroll
    for (int nf = 0; nf < NI; ++nf)
#pragma unroll
      for (int r = 0; r < 4; ++r) {
        const size_t idx = (size_t)(crow0 + mf * 16 + r) * N + ccol0 + nf * 16;
        if (BF16_OUT) ((u16*)Cv)[idx]   = f2bf(acc[mf][nf][r]);
        else          ((float*)Cv)[idx] = acc[mf][nf][r];
      }
}

// ------------------- Spart partials + last-block fold -> S ------------------
// grid (32 bh, 16 chunks of 128 rows).  Each block writes its 64x64 partial;
// the last block of each bh (atomic flag) folds the 16 partials into S.
// Release/acquire via __threadfence() around the flag (device-scope).
__global__ __launch_bounds__(256) void s_kernel(const u16* __restrict__ QKV,
                                                float* __restrict__ Spart,
                                                float* __restrict__ S,
                                                int* __restrict__ cnt) {
  const int bh = blockIdx.x;
  const int b = bh >> 4, hh = bh & 15;
  const int row0 = b * 2048 + blockIdx.y * 128;
  const u16* Kg = QKV + (size_t)row0 * 3072 + 1024 + hh * 64;

  __shared__ float Ks[64][64];
  __shared__ float Vs[64][64];
  const int t = threadIdx.x;
  const int lr = t >> 2;        // 0..63 row within stage
  const int lc = (t & 3) * 16;  // col group (16 cols)
  const int d1 = (t >> 4) * 4;
  const int d2 = (t & 15) * 4;

  float acc[4][4] = {};

  for (int r0 = 0; r0 < 128; r0 += 64) {
    const u16* kp = Kg + (size_t)(r0 + lr) * 3072 + lc;
    const uint4 kw0 = *(const uint4*)kp;
    const uint4 kw1 = *(const uint4*)(kp + 8);
    const uint4 vw0 = *(const uint4*)(kp + 1024);  // V = K + 1024 cols
    const uint4 vw1 = *(const uint4*)(kp + 1032);
    __syncthreads();  // prev-iter readers done
    float* kd = &Ks[lr][lc];
    *(float4*)(kd)      = float4{bflo(kw0.x), bfhi(kw0.x), bflo(kw0.y), bfhi(kw0.y)};
    *(float4*)(kd + 4)  = float4{bflo(kw0.z), bfhi(kw0.z), bflo(kw0.w), bfhi(kw0.w)};
    *(float4*)(kd + 8)  = float4{bflo(kw1.x), bfhi(kw1.x), bflo(kw1.y), bfhi(kw1.y)};
    *(float4*)(kd + 12) = float4{bflo(kw1.z), bfhi(kw1.z), bflo(kw1.w), bfhi(kw1.w)};
    float* vd = &Vs[lr][lc];
    *(float4*)(vd)      = float4{bflo(vw0.x), bfhi(vw0.x), bflo(vw0.y), bfhi(vw0.y)};
    *(float4*)(vd + 4)  = float4{bflo(vw0.z), bfhi(vw0.z), bflo(vw0.w), bfhi(vw0.w)};
    *(float4*)(vd + 8)  = float4{bflo(vw1.x), bfhi(vw1.x), bflo(vw1.y), bfhi(vw1.y)};
    *(float4*)(vd + 12) = float4{bflo(vw1.z), bfhi(vw1.z), bflo(vw1.w), bfhi(vw1.w)};
    __syncthreads();
#pragma unroll
    for (int r = 0; r < 64; ++r) {
      float kv[4], vv[4];
      *(float4*)kv = *(const float4*)&Ks[r][d1];
      *(float4*)vv = *(const float4*)&Vs[r][d2];
#pragma unroll
      for (int i = 0; i < 4; ++i)
#pragma unroll
        for (int j = 0; j < 4; ++j) acc[i][j] += kv[i] * vv[j];
    }
  }
  float* Sp = Spart + ((size_t)bh * 16 + blockIdx.y) * 4096;
#pragma unroll
  for (int i = 0; i < 4; ++i)
    *(float4*)&Sp[(d1 + i) * 64 + d2] =
        float4{acc[i][0], acc[i][1], acc[i][2], acc[i][3]};

  // ---- last-block fold ----
  __threadfence();                         // release: partial visible
  __shared__ int lastv;
  if (t == 0) lastv = (atomicAdd(&cnt[bh], 1) == 15);
  __syncthreads();
  if (!lastv) return;
  __threadfence();                         // acquire: see others' partials
  const float* base = Spart + (size_t)bh * 16 * 4096;
  float4 a[4] = {{0.f, 0.f, 0.f, 0.f}, {0.f, 0.f, 0.f, 0.f},
                 {0.f, 0.f, 0.f, 0.f}, {0.f, 0.f, 0.f, 0.f}};
#pragma unroll
  for (int c = 0; c < 16; ++c) {
    const float4* p = (const float4*)(base + (size_t)c * 4096) + t * 4;
#pragma unroll
    for (int i = 0; i < 4; ++i) {
      const float4 v = p[i];
      a[i].x += v.x; a[i].y += v.y; a[i].z += v.z; a[i].w += v.w;
    }
  }
  float4* So = (float4*)(S + (size_t)bh * 4096) + t * 4;
#pragma unroll
  for (int i = 0; i < 4; ++i) So[i] = a[i];
}

// ------------------------------------------- Tt = (S_h Wo_h^T)^T ------------
__global__ __launch_bounds__(256) void t_kernel(const float* __restrict__ S,
                                                const float* __restrict__ Wo,
                                                u16* __restrict__ Tt) {
  const int n0 = blockIdx.x * 128;
  const int hh = blockIdx.y;
  const int b  = blockIdx.z;
  __shared__ float Ss[64][68];
  __shared__ float Ws[128][68];
  const int t = threadIdx.x;
  {
    const float* sg = S + (size_t)(b * 16 + hh) * 4096 + (t >> 2) * 64 + (t & 3) * 16;
    float* sd = &Ss[t >> 2][(t & 3) * 16];
#pragma unroll
    for (int i = 0; i < 4; ++i) *(float4*)(sd + 4 * i) = *(const float4*)(sg + 4 * i);
    const float* wg = Wo + (size_t)(n0 + (t >> 1)) * 1024 + hh * 64 + (t & 1) * 32;
    float* wd = &Ws[t >> 1][(t & 1) * 32];
#pragma unroll
    for (int i = 0; i < 8; ++i) *(float4*)(wd + 4 * i) = *(const float4*)(wg + 4 * i);
  }
  __syncthreads();

  const int td = (t >> 4) * 4;  // d = td..td+3
  const int tn = t & 15;        // n = n0 + tn + 16k
  float acc[4][8] = {};
  for (int jj = 0; jj < 64; jj += 4) {
    float4 sv[4], wv[8];
#pragma unroll
    for (int i = 0; i < 4; ++i) sv[i] = *(const float4*)&Ss[td + i][jj];
#pragma unroll
    for (int k = 0; k < 8; ++k) wv[k] = *(const float4*)&Ws[tn + 16 * k][jj];
#pragma unroll
    for (int i = 0; i < 4; ++i)
#pragma unroll
      for (int k = 0; k < 8; ++k)
        acc[i][k] += sv[i].x * wv[k].x + sv[i].y * wv[k].y +
                     sv[i].z * wv[k].z + sv[i].w * wv[k].w;
  }

  u16* tp = Tt + (size_t)b * 1048576;
#pragma unroll
  for (int k = 0; k < 8; ++k) {
    const int n = n0 + tn + 16 * k;
    ushort4 o;
    o.x = f2bf(acc[0][k]); o.y = f2bf(acc[1][k]);
    o.z = f2bf(acc[2][k]); o.w = f2bf(acc[3][k]);
    *(ushort4*)&tp[(size_t)n * 1024 + hh * 64 + td] = o;
  }
}

// ---------------------------------------------------------------------------
extern "C" void kernel_launch(void* const* d_in, const int* in_sizes, int n_in,
                              void* d_out, int out_size, void* d_ws, size_t ws_size,
                              hipStream_t stream) {
  const float* h  = (const float*)d_in[0];  // (4096, 1024) fp32
  // d_in[1] = key_pe: dead branch in reference, unused.
  const float* Wq = (const float*)d_in[2];
  const float* Wk = (const float*)d_in[3];
  const float* Wv = (const float*)d_in[4];
  const float* Wo = (const float*)d_in[5];

  char* ws = (char*)d_ws;
  u16*   hb    = (u16*)(ws);                    // 4096*1024*2 = 8 MiB @ 0
  u16*   wcat  = (u16*)(ws + (8ull  << 20));    // 3072*1024*2 = 6 MiB
  u16*   QKVb  = (u16*)(ws + (16ull << 20));    // 4096*3072*2 = 24 MiB
  float* S     = (float*)(ws + (40ull << 20));  // 32*64*64*4  = 0.5 MiB
  u16*   Tt    = (u16*)(ws + (41ull << 20));    // 2*1024*1024*2 = 4 MiB
  float* Spart = (float*)(ws + (48ull << 20));  // 512*64*64*4 = 8 MiB
  int*   cnt   = (int*)(ws + (57ull << 20));    // 32 ints
  // total ws use: ~57 MiB (ws_size = 256 MiB)

  prep<<<7168, 256, 0, stream>>>((const float4*)h, (const float4*)Wq,
                                 (const float4*)Wk, (const float4*)Wv,
                                 (ushort4*)hb, (ushort4*)wcat, cnt);
  // QKVb = hb @ wcat^T : (4096 x 3072), K=1024, 256 blocks, 8 waves,
  // 160KB LDS -> 1 block/CU.
  gemmP<true, 384, 2><<<256, 512, 0, stream>>>(hb, 1024, wcat, nullptr,
                                               QKVb, 3072);
  s_kernel<<<dim3(32, 16), 256, 0, stream>>>(QKVb, Spart, S, cnt);
  t_kernel<<<dim3(8, 16, 2), 256, 0, stream>>>(S, Wo, Tt);
  // out = Q @ Tt_b^T : (4096 x 1024), K=1024, 256 blocks, 80KB LDS.
  gemmP<false, 128, 4><<<256, 512, 0, stream>>>(QKVb, 3072, Tt,
                                                Tt + 1048576, d_out, 1024);
}

// Round 11
// 152.092 us; speedup vs baseline: 1.3385x; 1.3385x over previous
//
#include <hip/hip_runtime.h>
#include <hip/hip_bf16.h>

// B=2, M=2048, HID=1024, NH=16, D=64.  No softmax in the reference, so
//   out = ((h Wq^T)(h Wk^T)^T (h Wv^T)) Wo^T
// reassociates twice:  S_{b,h} = K_h^T V_h  (64x64), and
//   out_b = Q_b @ T_b   with  T_b[h*64+d, n] = sum_j S_{b,h}[d,j] Wo[n, h*64+j]
//
// Dtypes: inputs fp32, d_out fp32; internal bf16 with fp32 accumulate.
//
// Round-22: r21's last-block fold REGRESSED -51us: s_kernel 71us (!), BW
// 0.3TB/s.  __threadfence() on gfx950 = device-scope L2 writeback/inv;
// 512 blocks x 2 fences serialized on the L2 and the acquire fence made
// the folder's 256KB partial-read miss L2.  Lesson: per-block device-scope
// fences cost more than the launch they save.  REVERTED to the r15
// pipeline (best measured, 151.5us).
// Salvage: r21's profile exposed s_kernel's SQ_LDS_BANK_CONFLICT=786432
// (present all along).  Ks/Vs rows were 256B = exact bank-period, so the
// 16 concurrently-written rows alias one bank group (~16-way write
// conflict).  r22 pads Ks/Vs to [64][68] (row 272B, still 16B-aligned ->
// float4 reads/writes legal; consecutive rows offset 4 banks -> ~4-way).
// Same fix t_kernel has used since r3.
// Lessons kept: no dense-reduction atomics (r6->r7); never trade
// high-occupancy FLOPs for low-occupancy FLOPs (r8); price redundant
// re-reads by XCD locality (r10); vmcnt waits are per-wave -- wait must
// precede a barrier (r12); count LDS bytes per phase (r13); grid must
// cover all 256 CUs (r14); don't serialize LDS and MFMA with explicit
// drains (r15); size the per-XCD L2 working set (r16); in-block schedule
// tweaks can't fix lockstep stalls (r17); when variants tie, cut work not
// tune (r18); FLOP cuts don't pay in the wait-bound regime (r19); when
// per-kernel tuning plateaus, cut LAUNCHES (r20) -- but never with
// per-block device-scope fences (r21).
//
// Pipeline:
//   0. prep: h->hb (bf16), Wq|Wk|Wv->wcat (bf16)
//   1. QKVb = hb @ wcat^T        (4096x3072 bf16)            [gemm32<384>]
//   2. Spart[bh,c] = K^T V partial over 128 rows             [VALU]
//   2b. S = sum_c Spart          (each line read once)       [BW]
//   3. Tt[b][n,k] = (S_h Wo_h^T)^T  (2 x 1024x1024 bf16)     [VALU]
//   4. out = Q @ Tt_b^T          (4096x1024 fp32 -> d_out)   [gemm32<128>]

typedef unsigned short u16;
typedef unsigned int u32;
typedef __attribute__((ext_vector_type(8))) short bf16x8;
typedef __attribute__((ext_vector_type(4))) float f32x4;

__device__ __forceinline__ void async_copy16(void* lds, const void* g) {
  __builtin_amdgcn_global_load_lds((const __attribute__((address_space(1))) void*)g,
                                   (__attribute__((address_space(3))) void*)lds,
                                   16, 0, 0);
}

__device__ __forceinline__ u16 f2bf(float f) {
  union { __hip_bfloat16 h; u16 u; } c;
  c.h = __float2bfloat16(f);
  return c.u;
}
__device__ __forceinline__ float bflo(u32 w) {
  union { u32 u; float f; } c; c.u = w << 16; return c.f;
}
__device__ __forceinline__ float bfhi(u32 w) {
  union { u32 u; float f; } c; c.u = w & 0xFFFF0000u; return c.f;
}
__device__ __forceinline__ ushort4 cvt4(float4 v) {
  ushort4 o; o.x = f2bf(v.x); o.y = f2bf(v.y); o.z = f2bf(v.z); o.w = f2bf(v.w);
  return o;
}

template <int N> __device__ __forceinline__ void vw() {
  if constexpr (N == 8)      asm volatile("s_waitcnt vmcnt(8)" ::: "memory");
  else if constexpr (N == 4) asm volatile("s_waitcnt vmcnt(4)" ::: "memory");
  else if constexpr (N == 2) asm volatile("s_waitcnt vmcnt(2)" ::: "memory");
  else if constexpr (N == 0) asm volatile("s_waitcnt vmcnt(0)" ::: "memory");
}

// ---------------------------------------------------------------- prep ------
__global__ __launch_bounds__(256) void prep(const float4* __restrict__ h,
                                            const float4* __restrict__ wq,
                                            const float4* __restrict__ wk,
                                            const float4* __restrict__ wv,
                                            ushort4* __restrict__ hb,
                                            ushort4* __restrict__ wcat) {
  int i = blockIdx.x * 256 + threadIdx.x;  // float4 units
  if (i < 1048576) { hb[i] = cvt4(h[i]); return; }          // h: 4096x1024
  i -= 1048576;
  if (i < 262144) { wcat[i] = cvt4(wq[i]); return; }
  i -= 262144;
  if (i < 262144) { wcat[262144 + i] = cvt4(wk[i]); return; }
  i -= 262144;
  wcat[524288 + i] = cvt4(wv[i]);
}

// ------------------------------ BK=32 4-buffer counted-vmcnt NT GEMM --------
// C[m,n] = sum_k A[m*lda+k] * B[n*1024+k], M=4096, K=1024.  BM=128 fixed.
// grid 256 = 32 m-tiles x 8 n-tiles (XCD-swizzled), 512 thr = 8 waves (2x4).
// One phase per K-tile: {MI+NI ds_read_b128 | stage tile kt+3 | lgkmcnt(0) |
// MI*NI MFMA (setprio) | vmcnt(2V) | s_barrier}.
// Safety (r14-verified): read buf kt&3 vs stage buf (kt+3)&3 always
// distinct; per-wave lgkmcnt(0) precedes the phase barrier (WAR-safe);
// tile kt+1 gated by all waves' vmcnt+barrier at end of phase kt.

#define NOPW ((void)0)

#define PHASE(KT, DO_STAGE, VWAIT)                                           \
  do {                                                                       \
    const u16* Ab = &Als[(KT) & 3][wm * 32 + aoff];                          \
    const u16* Bb = &Bls[(KT) & 3][wn * 32 + aoff];                          \
    bf16x8 af[MI], bv[NI];                                                   \
    _Pragma("unroll") for (int i = 0; i < MI; ++i)                           \
        af[i] = *(const bf16x8*)(Ab + i * 512);                              \
    _Pragma("unroll") for (int j = 0; j < NI; ++j)                           \
        bv[j] = *(const bf16x8*)(Bb + j * 512);                              \
    DO_STAGE;                                                                \
    asm volatile("s_waitcnt lgkmcnt(0)" ::: "memory");                       \
    __builtin_amdgcn_sched_barrier(0);                                       \
    __builtin_amdgcn_s_setprio(1);                                           \
    _Pragma("unroll") for (int i = 0; i < MI; ++i)                           \
        _Pragma("unroll") for (int j = 0; j < NI; ++j)                       \
            acc[i][j] = __builtin_amdgcn_mfma_f32_16x16x32_bf16(             \
                af[i], bv[j], acc[i][j], 0, 0, 0);                           \
    __builtin_amdgcn_s_setprio(0);                                           \
    VWAIT;                                                                   \
    __builtin_amdgcn_s_barrier();                                            \
  } while (0)

template <bool BF16_OUT, int BN>
__global__ __launch_bounds__(512, 2) void gemm32(const u16* __restrict__ A,
                                                 int lda,
                                                 const u16* __restrict__ B0,
                                                 const u16* __restrict__ B1,
                                                 void* __restrict__ Cv,
                                                 int N) {
  constexpr int SA = 1;              // A staging insts/thread (BM=128)
  constexpr int SB = BN / 128;       // B staging insts/thread
  constexpr int V  = SA + SB;        // insts/thread per tile
  constexpr int MI = 4;              // 64-row wave half -> 4 m-frags
  constexpr int NI = BN / 4 / 16;    // wave covers BN/4 cols

  __shared__ u16 Als[4][128 * 32];
  __shared__ u16 Bls[4][BN * 32];
  const int t = threadIdx.x;
  const int lane = t & 63;
  const int wave = t >> 6;                 // 0..7
  const int wm = (wave >> 2) * 64;         // 0 / 64
  const int wn = (wave & 3) * (BN / 4);    // mult of 16
  const int lrow = lane & 15;
  const int quad = lane >> 4;

  // bijective XCD swizzle (256 blocks): XCD x -> m-tiles {4x..4x+3} x all 8 n
  const int bid = blockIdx.x;
  const int xcd = bid & 7;
  const int c = bid >> 3;                  // 0..31
  const int m0 = (xcd * 4 + (c >> 3)) * 128;
  const int n0 = (c & 7) * BN;
  const u16* B = (B1 != nullptr && m0 >= 2048) ? B1 : B0;

  // staging: one inst = 16 rows x 32 k = 1 KB; lane l -> row +(l>>2),
  // LDS slot l&3 holding global k-granule (l&3)^((l>>3)&3)  (linear dest).
  const int srow = lane >> 2;                       // 0..15
  const int sgk  = (lane & 3) ^ ((lane >> 3) & 3);  // global k-granule
  const u16* Ag = A + (size_t)(m0 + wave * (SA * 16) + srow) * lda + sgk * 8;
  const u16* Bg = B + (size_t)(n0 + wave * (SB * 16) + srow) * 1024 + sgk * 8;

  // read swizzle: slot holding granule `quad` at row r is quad^((r>>1)&3);
  // all row bases are multiples of 16, so (r>>1)&3 == (lrow>>1)&3.
  const int swz = (lrow >> 1) & 3;
  const int aoff = lrow * 32 + ((quad ^ swz) << 3);  // u16 units

  f32x4 acc[MI][NI];
#pragma unroll
  for (int i = 0; i < MI; ++i)
#pragma unroll
    for (int j = 0; j < NI; ++j) acc[i][j] = {0.f, 0.f, 0.f, 0.f};

  // stage tile kt (V insts/thread: SA for A, SB for B) into buf kt&3
  auto stage = [&](int kt) {
    const int buf = kt & 3;
#pragma unroll
    for (int j = 0; j < SA; ++j) {
      const int ch = wave * SA + j;                  // 16-row chunk index
      async_copy16(&Als[buf][ch * 512 + lane * 8],
                   Ag + (size_t)(j * 16) * lda + kt * 32);
    }
#pragma unroll
    for (int j = 0; j < SB; ++j) {
      const int ch = wave * SB + j;
      async_copy16(&Bls[buf][ch * 512 + lane * 8],
                   Bg + (size_t)(j * 16) * 1024 + kt * 32);
    }
  };

  // prologue: stage tiles 0,1,2 (3V insts); wait tile0 (<=2V left); barrier.
  stage(0); stage(1); stage(2);
  vw<2 * V>();
  __builtin_amdgcn_s_barrier();

  // steady: phase kt stages kt+3 (3V in flight), vw<2V> drains tile kt+1.
#pragma unroll 1
  for (int kt = 0; kt < 29; ++kt) {
    PHASE(kt, stage(kt + 3), vw<2 * V>());
  }
  PHASE(29, NOPW, vw<V>());   // in flight: t30,t31 -> drain t30
  PHASE(30, NOPW, vw<0>());   // drain t31
  PHASE(31, NOPW, NOPW);

  // C/D layout (verified m89/m91): col = lane&15, row = (lane>>4)*4 + r
  const int crow0 = m0 + wm + quad * 4;
  const int ccol0 = n0 + wn + lrow;
#pragma unroll
  for (int mf = 0; mf < MI; ++mf)
#pragma unroll
    for (int nf = 0; nf < NI; ++nf)
#pragma unroll
      for (int r = 0; r < 4; ++r) {
        const size_t idx = (size_t)(crow0 + mf * 16 + r) * N + ccol0 + nf * 16;
        if (BF16_OUT) ((u16*)Cv)[idx]   = f2bf(acc[mf][nf][r]);
        else          ((float*)Cv)[idx] = acc[mf][nf][r];
      }
}

// --------------------------------------------- Spart = partial K^T V --------
// r22: Ks/Vs padded [64][68] -- rows were 256B (exact bank period) giving
// ~16-way WRITE conflicts (786K SQ_LDS_BANK_CONFLICT, r21 profile); 272B
// rows stay 16B-aligned (float4 ops legal) and offset rows by 4 banks.
__global__ __launch_bounds__(256) void s_kernel(const u16* __restrict__ QKV,
                                                float* __restrict__ Spart) {
  const int bh = blockIdx.x;
  const int b = bh >> 4, hh = bh & 15;
  const int row0 = b * 2048 + blockIdx.y * 128;
  const u16* Kg = QKV + (size_t)row0 * 3072 + 1024 + hh * 64;

  __shared__ float Ks[64][68];
  __shared__ float Vs[64][68];
  const int t = threadIdx.x;
  const int lr = t >> 2;        // 0..63 row within stage
  const int lc = (t & 3) * 16;  // col group (16 cols)
  const int d1 = (t >> 4) * 4;
  const int d2 = (t & 15) * 4;

  float acc[4][4] = {};

  for (int r0 = 0; r0 < 128; r0 += 64) {
    const u16* kp = Kg + (size_t)(r0 + lr) * 3072 + lc;
    const uint4 kw0 = *(const uint4*)kp;
    const uint4 kw1 = *(const uint4*)(kp + 8);
    const uint4 vw0 = *(const uint4*)(kp + 1024);  // V = K + 1024 cols
    const uint4 vw1 = *(const uint4*)(kp + 1032);
    __syncthreads();  // prev-iter readers done
    float* kd = &Ks[lr][lc];
    *(float4*)(kd)      = float4{bflo(kw0.x), bfhi(kw0.x), bflo(kw0.y), bfhi(kw0.y)};
    *(float4*)(kd + 4)  = float4{bflo(kw0.z), bfhi(kw0.z), bflo(kw0.w), bfhi(kw0.w)};
    *(float4*)(kd + 8)  = float4{bflo(kw1.x), bfhi(kw1.x), bflo(kw1.y), bfhi(kw1.y)};
    *(float4*)(kd + 12) = float4{bflo(kw1.z), bfhi(kw1.z), bflo(kw1.w), bfhi(kw1.w)};
    float* vd = &Vs[lr][lc];
    *(float4*)(vd)      = float4{bflo(vw0.x), bfhi(vw0.x), bflo(vw0.y), bfhi(vw0.y)};
    *(float4*)(vd + 4)  = float4{bflo(vw0.z), bfhi(vw0.z), bflo(vw0.w), bfhi(vw0.w)};
    *(float4*)(vd + 8)  = float4{bflo(vw1.x), bfhi(vw1.x), bflo(vw1.y), bfhi(vw1.y)};
    *(float4*)(vd + 12) = float4{bflo(vw1.z), bfhi(vw1.z), bflo(vw1.w), bfhi(vw1.w)};
    __syncthreads();
#pragma unroll
    for (int r = 0; r < 64; ++r) {
      float kv[4], vv[4];
      *(float4*)kv = *(const float4*)&Ks[r][d1];
      *(float4*)vv = *(const float4*)&Vs[r][d2];
#pragma unroll
      for (int i = 0; i < 4; ++i)
#pragma unroll
        for (int j = 0; j < 4; ++j) acc[i][j] += kv[i] * vv[j];
    }
  }
  float* Sp = Spart + ((size_t)bh * 16 + blockIdx.y) * 4096;
#pragma unroll
  for (int i = 0; i < 4; ++i)
    *(float4*)&Sp[(d1 + i) * 64 + d2] =
        float4{acc[i][0], acc[i][1], acc[i][2], acc[i][3]};
}

// ---------------------------------------------------- S = sum_c Spart -------
__global__ __launch_bounds__(256) void reduce_s(const float4* __restrict__ Spart,
                                                float4* __restrict__ S) {
  const int g = blockIdx.x * 256 + threadIdx.x;  // 0..32767
  const int bh = g >> 10, j = g & 1023;
  const float4* p = Spart + (size_t)bh * 16384 + j;  // 16 chunks * 1024 f4
  float4 a = {0.f, 0.f, 0.f, 0.f};
#pragma unroll
  for (int c = 0; c < 16; ++c) {
    const float4 v = p[(size_t)c * 1024];
    a.x += v.x; a.y += v.y; a.z += v.z; a.w += v.w;
  }
  S[g] = a;
}

// ------------------------------------------- Tt = (S_h Wo_h^T)^T ------------
__global__ __launch_bounds__(256) void t_kernel(const float* __restrict__ S,
                                                const float* __restrict__ Wo,
                                                u16* __restrict__ Tt) {
  const int n0 = blockIdx.x * 128;
  const int hh = blockIdx.y;
  const int b  = blockIdx.z;
  __shared__ float Ss[64][68];
  __shared__ float Ws[128][68];
  const int t = threadIdx.x;
  {
    const float* sg = S + (size_t)(b * 16 + hh) * 4096 + (t >> 2) * 64 + (t & 3) * 16;
    float* sd = &Ss[t >> 2][(t & 3) * 16];
#pragma unroll
    for (int i = 0; i < 4; ++i) *(float4*)(sd + 4 * i) = *(const float4*)(sg + 4 * i);
    const float* wg = Wo + (size_t)(n0 + (t >> 1)) * 1024 + hh * 64 + (t & 1) * 32;
    float* wd = &Ws[t >> 1][(t & 1) * 32];
#pragma unroll
    for (int i = 0; i < 8; ++i) *(float4*)(wd + 4 * i) = *(const float4*)(wg + 4 * i);
  }
  __syncthreads();

  const int td = (t >> 4) * 4;  // d = td..td+3
  const int tn = t & 15;        // n = n0 + tn + 16k
  float acc[4][8] = {};
  for (int jj = 0; jj < 64; jj += 4) {
    float4 sv[4], wv[8];
#pragma unroll
    for (int i = 0; i < 4; ++i) sv[i] = *(const float4*)&Ss[td + i][jj];
#pragma unroll
    for (int k = 0; k < 8; ++k) wv[k] = *(const float4*)&Ws[tn + 16 * k][jj];
#pragma unroll
    for (int i = 0; i < 4; ++i)
#pragma unroll
      for (int k = 0; k < 8; ++k)
        acc[i][k] += sv[i].x * wv[k].x + sv[i].y * wv[k].y +
                     sv[i].z * wv[k].z + sv[i].w * wv[k].w;
  }

  u16* tp = Tt + (size_t)b * 1048576;
#pragma unroll
  for (int k = 0; k < 8; ++k) {
    const int n = n0 + tn + 16 * k;
    ushort4 o;
    o.x = f2bf(acc[0][k]); o.y = f2bf(acc[1][k]);
    o.z = f2bf(acc[2][k]); o.w = f2bf(acc[3][k]);
    *(ushort4*)&tp[(size_t)n * 1024 + hh * 64 + td] = o;
  }
}

// ---------------------------------------------------------------------------
extern "C" void kernel_launch(void* const* d_in, const int* in_sizes, int n_in,
                              void* d_out, int out_size, void* d_ws, size_t ws_size,
                              hipStream_t stream) {
  const float* h  = (const float*)d_in[0];  // (4096, 1024) fp32
  // d_in[1] = key_pe: dead branch in reference, unused.
  const float* Wq = (const float*)d_in[2];
  const float* Wk = (const float*)d_in[3];
  const float* Wv = (const float*)d_in[4];
  const float* Wo = (const float*)d_in[5];

  char* ws = (char*)d_ws;
  u16*   hb    = (u16*)(ws);                    // 4096*1024*2 = 8 MiB @ 0
  u16*   wcat  = (u16*)(ws + (8ull  << 20));    // 3072*1024*2 = 6 MiB
  u16*   QKVb  = (u16*)(ws + (16ull << 20));    // 4096*3072*2 = 24 MiB
  float* S     = (float*)(ws + (40ull << 20));  // 32*64*64*4  = 0.5 MiB
  u16*   Tt    = (u16*)(ws + (41ull << 20));    // 2*1024*1024*2 = 4 MiB
  float* Spart = (float*)(ws + (48ull << 20));  // 512*64*64*4 = 8 MiB
  // total ws use: 56 MiB (ws_size = 256 MiB)

  prep<<<7168, 256, 0, stream>>>((const float4*)h, (const float4*)Wq,
                                 (const float4*)Wk, (const float4*)Wv,
                                 (ushort4*)hb, (ushort4*)wcat);
  // QKVb = hb @ wcat^T : (4096 x 3072), K=1024, 256 blocks = 1/CU, 8 waves
  gemm32<true, 384><<<256, 512, 0, stream>>>(hb, 1024, wcat, nullptr,
                                             QKVb, 3072);
  s_kernel<<<dim3(32, 16), 256, 0, stream>>>(QKVb, Spart);
  reduce_s<<<128, 256, 0, stream>>>((const float4*)Spart, (float4*)S);
  t_kernel<<<dim3(8, 16, 2), 256, 0, stream>>>(S, Wo, Tt);
  // out = Q @ Tt_b^T : (4096 x 1024), K=1024, 256 blocks = 1/CU, 8 waves
  gemm32<false, 128><<<256, 512, 0, stream>>>(QKVb, 3072, Tt, Tt + 1048576,
                                              d_out, 1024);
}